// Round 3
// baseline (614.509 us; speedup 1.0000x reference)
//
#include <hip/hip_runtime.h>
#include <float.h>

#define N_TOK 262144
#define N_E   1024
#define E_DIM 64
#define BETA  0.25f

// ---------------------------------------------------------------------------
// Bit-exact replica of numpy f32: out = np.sum(v*v) over 64 contiguous f32.
// numpy reduce (no initial): out = q0 + pairwise_sum(q[1:], n=63) where
// pairwise_sum (n<=PW_BLOCKSIZE) = 8-accumulator scheme:
//   r[t] = b[t]; for i=8,16,..,48: r[t]+=b[i+t];
//   res = ((r0+r1)+(r2+r3))+((r4+r5)+(r6+r7)); then res += b[56..62] seq.
// All products/sums individually rounded (no fma) -> __fmul_rn/__fadd_rn.
// ---------------------------------------------------------------------------
__device__ __forceinline__ float np_sumsq64(const float v[E_DIM])
{
    float r[8];
#pragma unroll
    for (int t = 0; t < 8; ++t) {
        float e = v[1 + t];
        r[t] = __fmul_rn(e, e);
    }
#pragma unroll
    for (int blk = 8; blk < 56; blk += 8) {
#pragma unroll
        for (int t = 0; t < 8; ++t) {
            float e = v[1 + blk + t];
            r[t] = __fadd_rn(r[t], __fmul_rn(e, e));
        }
    }
    float tA  = __fadd_rn(__fadd_rn(r[0], r[1]), __fadd_rn(r[2], r[3]));
    float tB  = __fadd_rn(__fadd_rn(r[4], r[5]), __fadd_rn(r[6], r[7]));
    float res = __fadd_rn(tA, tB);
#pragma unroll
    for (int k = 57; k < 64; ++k) {
        res = __fadd_rn(res, __fmul_rn(v[k], v[k]));
    }
    return __fadd_rn(__fmul_rn(v[0], v[0]), res);
}

// ---------------------------------------------------------------------------
// Prologue: s_c[j] = np-f32 sum(cb[j]^2); zero the loss slot (harness does
// not re-poison between replays; this kernel is ordered before vq_main).
// ---------------------------------------------------------------------------
__global__ __launch_bounds__(256) void vq_prep(const float* __restrict__ cb,
                                               float* __restrict__ scn,
                                               float* __restrict__ loss_slot)
{
    int j = blockIdx.x * 256 + threadIdx.x;
    if (j < N_E) {
        const float* c = cb + (size_t)j * E_DIM;
        float cr[E_DIM];
#pragma unroll
        for (int k = 0; k < E_DIM; k += 4) {
            float4 v = *(const float4*)(c + k);
            cr[k] = v.x; cr[k + 1] = v.y; cr[k + 2] = v.z; cr[k + 3] = v.w;
        }
        scn[j] = np_sumsq64(cr);
    }
    if (blockIdx.x == 0 && threadIdx.x == 0) *loss_slot = 0.f;
}

// ---------------------------------------------------------------------------
// Main: one token/thread. Replicates the np f32 distance bit-exactly:
//   m_j  : ascending-k sequential fmaf chain (BLAS sgemm microkernel order)
//   d_j  = f32( f32(s_x + s_c_j) - f32(2*m_j) )
//   argmin: strict <, ascending j (numpy first-occurrence)
// JU=2 independent chains for ILP; codebook addresses are wave-uniform
// (scalar-load broadcast operands).
// ---------------------------------------------------------------------------
__global__ __launch_bounds__(256, 4) void vq_main(const float* __restrict__ x,
                                                  const float* __restrict__ cb,
                                                  const float* __restrict__ scn,
                                                  float* __restrict__ xq_out,
                                                  float* __restrict__ loss_out,
                                                  float* __restrict__ idx_out)
{
    const int tok = blockIdx.x * blockDim.x + threadIdx.x;

    float xr[E_DIM];
    {
        const float* xrow = x + (size_t)tok * E_DIM;
#pragma unroll
        for (int k = 0; k < E_DIM; k += 4) {
            float4 v = *(const float4*)(xrow + k);
            xr[k] = v.x; xr[k + 1] = v.y; xr[k + 2] = v.z; xr[k + 3] = v.w;
        }
    }

    const float sx = np_sumsq64(xr);

    float dmin = FLT_MAX;
    int   imin = 0;

    for (int j = 0; j < N_E; j += 2) {
        const float* c0 = cb + (size_t)j * E_DIM;   // wave-uniform addresses
        const float* c1 = c0 + E_DIM;
        float m0 = 0.f, m1 = 0.f;                   // sequential k-chains (BLAS order)
#pragma unroll
        for (int k = 0; k < E_DIM; ++k) {
            m0 = fmaf(xr[k], c0[k], m0);
            m1 = fmaf(xr[k], c1[k], m1);
        }
        float d0 = __fsub_rn(__fadd_rn(sx, scn[j]),     __fmul_rn(2.0f, m0));
        float d1 = __fsub_rn(__fadd_rn(sx, scn[j + 1]), __fmul_rn(2.0f, m1));
        if (d0 < dmin) { dmin = d0; imin = j; }
        if (d1 < dmin) { dmin = d1; imin = j + 1; }
    }

    // Epilogue: gather winning codebook row (256 KB table, L2-resident).
    float lsum = 0.f;
    {
        const float* cmin = cb + (size_t)imin * E_DIM;  // per-lane address
        float*       xq   = xq_out + (size_t)tok * E_DIM;
#pragma unroll
        for (int k = 0; k < E_DIM; k += 4) {
            float4 cv = *(const float4*)(cmin + k);
            *(float4*)(xq + k) = cv;                    // forward x_q_st == x_q
            float d0 = cv.x - xr[k    ];
            float d1 = cv.y - xr[k + 1];
            float d2 = cv.z - xr[k + 2];
            float d3 = cv.w - xr[k + 3];
            lsum = fmaf(d0, d0, lsum);
            lsum = fmaf(d1, d1, lsum);
            lsum = fmaf(d2, d2, lsum);
            lsum = fmaf(d3, d3, lsum);
        }
    }
    idx_out[tok] = (float)imin;   // exact integer in f32

    // Loss: 64-lane shuffle tree, cross-wave via LDS, one atomic per block.
    for (int m = 1; m < 64; m <<= 1) lsum += __shfl_xor(lsum, m, 64);
    __shared__ float red[4];
    const int lane = threadIdx.x & 63;
    const int wid  = threadIdx.x >> 6;
    if (lane == 0) red[wid] = lsum;
    __syncthreads();
    if (threadIdx.x == 0) {
        float part = red[0] + red[1] + red[2] + red[3];
        const float scale = (1.0f + BETA) / ((float)N_TOK * (float)E_DIM);
        atomicAdd(loss_out, part * scale);
    }
}

extern "C" void kernel_launch(void* const* d_in, const int* in_sizes, int n_in,
                              void* d_out, int out_size, void* d_ws, size_t ws_size,
                              hipStream_t stream)
{
    const float* x  = (const float*)d_in[0];   // [262144, 64] f32
    const float* cb = (const float*)d_in[1];   // [1024, 64]   f32

    float* out  = (float*)d_out;
    float* xq   = out;                              // 262144*64 floats
    float* loss = out + (size_t)N_TOK * E_DIM;      // 1 float
    float* idx  = loss + 1;                         // 262144 floats

    float* scn = (float*)d_ws;                      // 1024 floats scratch

    vq_prep<<<N_E / 256, 256, 0, stream>>>(cb, scn, loss);
    vq_main<<<N_TOK / 256, 256, 0, stream>>>(x, cb, scn, xq, loss, idx);
}